// Round 2
// baseline (1248.048 us; speedup 1.0000x reference)
//
#include <hip/hip_runtime.h>
#include <math.h>

#define NFEAT 128
#define EPSBN 1e-5f

// ---------------------------------------------------------------------------
// K1: P_w = feature @ W_w + b_w + feature   for w in {s,i,r}
//     plus per-column sum / sumsq (for BatchNorm batch stats)
// grid = 3 * ceil(N/128) blocks, 256 threads.  bid%3 selects the weight.
// ---------------------------------------------------------------------------
__global__ __launch_bounds__(256, 2) void k1_gemm(
    const float* __restrict__ feat,
    const float* __restrict__ Ws, const float* __restrict__ bs,
    const float* __restrict__ Wi, const float* __restrict__ bi,
    const float* __restrict__ Wr, const float* __restrict__ br,
    float* __restrict__ Pout,    // 3 consecutive N x 128 matrices
    float* __restrict__ stats,   // 6*128: sum_s, ssq_s, sum_i, ssq_i, sum_r, ssq_r
    int N)
{
  const int bid = blockIdx.x;
  const int wi  = bid % 3;
  const int rb  = bid / 3;
  const int row0 = rb * 128;

  const float* W    = (wi == 0) ? Ws : ((wi == 1) ? Wi : Wr);
  const float* bias = (wi == 0) ? bs : ((wi == 1) ? bi : br);
  float* P    = Pout  + (size_t)wi * N * NFEAT;
  float* sump = stats + wi * 256;
  float* ssqp = sump + 128;

  __shared__ float Ach[128 * 32];   // 16 KB  A chunk, row-major [r][k]
  __shared__ float Wch[32 * 128];   // 16 KB  W chunk, row-major [k][c]
  __shared__ float red[16 * 128];   //  8 KB  stats reduction

  const int tid = threadIdx.x;
  const int rg = tid >> 4;          // 0..15 -> 8 rows each
  const int cg = tid & 15;          // 0..15 -> cols {4cg..4cg+3} u {64+4cg..}
  const int r0 = rg * 8;
  const int c0 = cg * 4;
  const int c1 = 64 + c0;

  float4 accA[8], accB[8];
#pragma unroll
  for (int j = 0; j < 8; j++) {
    accA[j] = make_float4(0.f, 0.f, 0.f, 0.f);
    accB[j] = make_float4(0.f, 0.f, 0.f, 0.f);
  }

  for (int kk = 0; kk < 4; kk++) {
    __syncthreads();
    // stage A chunk: Ach[r][k] = feat[row0+r][kk*32+k]
#pragma unroll
    for (int i = 0; i < 4; i++) {
      int q = i * 256 + tid;              // 0..1023 float4 slots
      int r = q >> 3;
      int k4 = (q & 7) * 4;
      int rs = row0 + r; if (rs >= N) rs = N - 1;
      *(float4*)&Ach[r * 32 + k4] =
          *(const float4*)&feat[(size_t)rs * NFEAT + kk * 32 + k4];
    }
    // stage W chunk (linear 16 KB copy)
#pragma unroll
    for (int i = 0; i < 4; i++) {
      int q = i * 256 + tid;
      *(float4*)&Wch[q * 4] = *(const float4*)&W[(size_t)kk * 4096 + q * 4];
    }
    __syncthreads();

#pragma unroll
    for (int k4 = 0; k4 < 32; k4 += 4) {
      float4 a[8];
#pragma unroll
      for (int j = 0; j < 8; j++)
        a[j] = *(float4*)&Ach[(r0 + j) * 32 + k4];
#pragma unroll
      for (int t = 0; t < 4; t++) {
        float4 w0 = *(float4*)&Wch[(k4 + t) * 128 + c0];
        float4 w1 = *(float4*)&Wch[(k4 + t) * 128 + c1];
#pragma unroll
        for (int j = 0; j < 8; j++) {
          float av = (t == 0) ? a[j].x : (t == 1) ? a[j].y : (t == 2) ? a[j].z : a[j].w;
          accA[j].x = fmaf(av, w0.x, accA[j].x);
          accA[j].y = fmaf(av, w0.y, accA[j].y);
          accA[j].z = fmaf(av, w0.z, accA[j].z);
          accA[j].w = fmaf(av, w0.w, accA[j].w);
          accB[j].x = fmaf(av, w1.x, accB[j].x);
          accB[j].y = fmaf(av, w1.y, accB[j].y);
          accB[j].z = fmaf(av, w1.z, accB[j].z);
          accB[j].w = fmaf(av, w1.w, accB[j].w);
        }
      }
    }
  }

  // epilogue: + bias + residual, store, column partial sums
  float4 b0 = *(const float4*)&bias[c0];
  float4 b1 = *(const float4*)&bias[c1];
  float4 cs0 = make_float4(0,0,0,0), cq0 = make_float4(0,0,0,0);
  float4 cs1 = make_float4(0,0,0,0), cq1 = make_float4(0,0,0,0);
#pragma unroll
  for (int j = 0; j < 8; j++) {
    int r = row0 + r0 + j;
    if (r < N) {
      float4 f0 = *(const float4*)&feat[(size_t)r * NFEAT + c0];
      float4 f1 = *(const float4*)&feat[(size_t)r * NFEAT + c1];
      float4 v0, v1;
      v0.x = accA[j].x + b0.x + f0.x;  v0.y = accA[j].y + b0.y + f0.y;
      v0.z = accA[j].z + b0.z + f0.z;  v0.w = accA[j].w + b0.w + f0.w;
      v1.x = accB[j].x + b1.x + f1.x;  v1.y = accB[j].y + b1.y + f1.y;
      v1.z = accB[j].z + b1.z + f1.z;  v1.w = accB[j].w + b1.w + f1.w;
      *(float4*)&P[(size_t)r * NFEAT + c0] = v0;
      *(float4*)&P[(size_t)r * NFEAT + c1] = v1;
      cs0.x += v0.x; cs0.y += v0.y; cs0.z += v0.z; cs0.w += v0.w;
      cs1.x += v1.x; cs1.y += v1.y; cs1.z += v1.z; cs1.w += v1.w;
      cq0.x += v0.x*v0.x; cq0.y += v0.y*v0.y; cq0.z += v0.z*v0.z; cq0.w += v0.w*v0.w;
      cq1.x += v1.x*v1.x; cq1.y += v1.y*v1.y; cq1.z += v1.z*v1.z; cq1.w += v1.w*v1.w;
    }
  }

  // block-level column reduce, then one atomic per column per block
  *(float4*)&red[rg * 128 + c0] = cs0;
  *(float4*)&red[rg * 128 + c1] = cs1;
  __syncthreads();
  if (tid < 128) {
    float s = 0.f;
#pragma unroll
    for (int g = 0; g < 16; g++) s += red[g * 128 + tid];
    unsafeAtomicAdd(&sump[tid], s);
  }
  __syncthreads();
  *(float4*)&red[rg * 128 + c0] = cq0;
  *(float4*)&red[rg * 128 + c1] = cq1;
  __syncthreads();
  if (tid < 128) {
    float s = 0.f;
#pragma unroll
    for (int g = 0; g < 16; g++) s += red[g * 128 + tid];
    unsafeAtomicAdd(&ssqp[tid], s);
  }
}

// ---------------------------------------------------------------------------
// K2: one block. BN scale/shift per column for the 3 matrices, and fold the
// entire linear back-half into 4 F x 3 matrices + 3-vector bias:
//   logits = S@M1 + I@M3 + R@M4 + NB@M2 + cb
// MT layout: MT[cl*512 + part*128 + k], part: 0=S 1=I 2=R 3=NB
// ---------------------------------------------------------------------------
__global__ void k2_params(
    const float* __restrict__ stats,
    const float* __restrict__ gamma, const float* __restrict__ beta,
    const float* __restrict__ WtoI, const float* __restrict__ btoI,
    const float* __restrict__ WtoR, const float* __restrict__ btoR,
    const float* __restrict__ Wout, const float* __restrict__ bout,
    float* __restrict__ bn,   // 6*128: [w]{a[128], b[128]}
    float* __restrict__ MT,   // 3*512
    float* __restrict__ cb,   // 4
    int N)
{
  const int tid = threadIdx.x;
  const float invN = 1.0f / (float)N;

  for (int t = tid; t < 384; t += 256) {
    int w = t >> 7, c = t & 127;
    float sm = stats[w * 256 + c];
    float sq = stats[w * 256 + 128 + c];
    float m = sm * invN;
    float v = sq * invN - m * m;
    float rinv = rsqrtf(v + EPSBN);
    float a = gamma[c] * rinv;
    bn[w * 256 + c] = a;
    bn[w * 256 + 128 + c] = beta[c] - m * a;
  }

  for (int t = tid; t < 1536; t += 256) {
    int cl = t / 512;
    int idx = t - cl * 512;
    int part = idx >> 7, k = idx & 127;
    float val;
    if (part == 0) {            // S: Wo1 + WtoI_top @ (Wo2-Wo1)
      float s = Wout[k * 3 + cl];
      for (int f = 0; f < 128; f++)
        s = fmaf(WtoI[k * 128 + f],
                 Wout[(128 + f) * 3 + cl] - Wout[f * 3 + cl], s);
      val = s;
    } else if (part == 1) {     // I: Wo2 + WtoR @ (Wo3-Wo2)
      float s = Wout[(128 + k) * 3 + cl];
      for (int f = 0; f < 128; f++)
        s = fmaf(WtoR[k * 128 + f],
                 Wout[(256 + f) * 3 + cl] - Wout[(128 + f) * 3 + cl], s);
      val = s;
    } else if (part == 2) {     // R: Wo3
      val = Wout[(256 + k) * 3 + cl];
    } else {                    // NB: WtoI_bot @ (Wo2-Wo1)
      float s = 0.f;
      for (int f = 0; f < 128; f++)
        s = fmaf(WtoI[(128 + k) * 128 + f],
                 Wout[(128 + f) * 3 + cl] - Wout[f * 3 + cl], s);
      val = s;
    }
    MT[cl * 512 + idx] = val;
  }

  if (tid < 3) {
    float s = bout[tid];
    for (int f = 0; f < 128; f++) {
      s = fmaf(btoI[f], Wout[(128 + f) * 3 + tid] - Wout[f * 3 + tid], s);
      s = fmaf(btoR[f], Wout[(256 + f) * 3 + tid] - Wout[(128 + f) * 3 + tid], s);
    }
    cb[tid] = s;
  }
}

// ---------------------------------------------------------------------------
// K3: edge scatter.  NB[dst] += relu(bn_i(P_i[src])) * w   (32 lanes / edge)
// ---------------------------------------------------------------------------
__global__ __launch_bounds__(256) void k3_scatter(
    const float* __restrict__ Pi,
    const int* __restrict__ eidx, const float* __restrict__ ew,
    const float* __restrict__ bn,
    float* __restrict__ NB, int E)
{
  long gid = (long)blockIdx.x * 256 + threadIdx.x;
  int e = (int)(gid >> 5);
  if (e >= E) return;
  int c = (threadIdx.x & 31) * 4;

  int src = eidx[e];
  int dst = eidx[E + e];
  float w = ew[e];

  float4 x = *(const float4*)&Pi[(size_t)src * NFEAT + c];
  float4 a = *(const float4*)&bn[256 + c];        // w==1 (i) scale
  float4 b = *(const float4*)&bn[256 + 128 + c];  // w==1 (i) shift

  float m0 = fmaxf(fmaf(a.x, x.x, b.x), 0.f) * w;
  float m1 = fmaxf(fmaf(a.y, x.y, b.y), 0.f) * w;
  float m2 = fmaxf(fmaf(a.z, x.z, b.z), 0.f) * w;
  float m3 = fmaxf(fmaf(a.w, x.w, b.w), 0.f) * w;

  float* o = NB + (size_t)dst * NFEAT + c;
  unsafeAtomicAdd(o + 0, m0);
  unsafeAtomicAdd(o + 1, m1);
  unsafeAtomicAdd(o + 2, m2);
  unsafeAtomicAdd(o + 3, m3);
}

// ---------------------------------------------------------------------------
// K4: per-row fused BN+ReLU, 512x3 dot with folded MT, softmax.
// 16 lanes per row (4 matrix-parts x 4 segments), 16 rows per 256-thr block.
// ---------------------------------------------------------------------------
__global__ __launch_bounds__(256) void k4_final(
    const float* __restrict__ P,   // 3 consecutive N x 128
    const float* __restrict__ NB,
    const float* __restrict__ bn,
    const float* __restrict__ MT,
    const float* __restrict__ cb,
    float* __restrict__ out, int N)
{
  __shared__ float MTs[1536];
  __shared__ float bns[768];
  const int tid = threadIdx.x;
  for (int i = tid; i < 1536; i += 256) MTs[i] = MT[i];
  for (int i = tid; i < 768; i += 256) bns[i] = bn[i];
  __syncthreads();

  const int row0 = blockIdx.x * 16 + (tid >> 4);
  const int row  = (row0 < N) ? row0 : (N - 1);
  const int p   = tid & 15;
  const int mp  = p >> 2;       // 0=S 1=I 2=R 3=NB
  const int seg = p & 3;        // 32-float segment

  const float* xsrc = (mp < 3)
      ? (P + ((size_t)mp * N + row) * NFEAT + seg * 32)
      : (NB + (size_t)row * NFEAT + seg * 32);

  float pa0 = 0.f, pa1 = 0.f, pa2 = 0.f;
#pragma unroll
  for (int i = 0; i < 8; i++) {
    float4 x = *(const float4*)&xsrc[i * 4];
    if (mp < 3) {
      int c = seg * 32 + i * 4;
      float4 a = *(float4*)&bns[mp * 256 + c];
      float4 b = *(float4*)&bns[mp * 256 + 128 + c];
      x.x = fmaxf(fmaf(a.x, x.x, b.x), 0.f);
      x.y = fmaxf(fmaf(a.y, x.y, b.y), 0.f);
      x.z = fmaxf(fmaf(a.z, x.z, b.z), 0.f);
      x.w = fmaxf(fmaf(a.w, x.w, b.w), 0.f);
    }
    int mo = mp * 128 + seg * 32 + i * 4;
    {
      float4 m = *(float4*)&MTs[0 * 512 + mo];
      pa0 += x.x * m.x + x.y * m.y + x.z * m.z + x.w * m.w;
    }
    {
      float4 m = *(float4*)&MTs[1 * 512 + mo];
      pa1 += x.x * m.x + x.y * m.y + x.z * m.z + x.w * m.w;
    }
    {
      float4 m = *(float4*)&MTs[2 * 512 + mo];
      pa2 += x.x * m.x + x.y * m.y + x.z * m.z + x.w * m.w;
    }
  }
#pragma unroll
  for (int off = 1; off < 16; off <<= 1) {
    pa0 += __shfl_xor(pa0, off);
    pa1 += __shfl_xor(pa1, off);
    pa2 += __shfl_xor(pa2, off);
  }
  if (p == 0 && row0 < N) {
    float l0 = pa0 + cb[0], l1 = pa1 + cb[1], l2 = pa2 + cb[2];
    float mx = fmaxf(l0, fmaxf(l1, l2));
    float e0 = expf(l0 - mx), e1 = expf(l1 - mx), e2 = expf(l2 - mx);
    float inv = 1.f / (e0 + e1 + e2);
    out[(size_t)row0 * 3 + 0] = e0 * inv;
    out[(size_t)row0 * 3 + 1] = e1 * inv;
    out[(size_t)row0 * 3 + 2] = e2 * inv;
  }
}

// ---------------------------------------------------------------------------
extern "C" void kernel_launch(void* const* d_in, const int* in_sizes, int n_in,
                              void* d_out, int out_size, void* d_ws, size_t ws_size,
                              hipStream_t stream)
{
  const float* feat  = (const float*)d_in[0];
  const int*   eidx  = (const int*)  d_in[1];
  const float* ew    = (const float*)d_in[2];
  const float* Ws    = (const float*)d_in[3];
  const float* bs    = (const float*)d_in[4];
  const float* Wi    = (const float*)d_in[5];
  const float* bi    = (const float*)d_in[6];
  const float* Wr    = (const float*)d_in[7];
  const float* br    = (const float*)d_in[8];
  const float* gamma = (const float*)d_in[9];
  const float* beta  = (const float*)d_in[10];
  const float* WtoI  = (const float*)d_in[11];
  const float* btoI  = (const float*)d_in[12];
  const float* WtoR  = (const float*)d_in[13];
  const float* btoR  = (const float*)d_in[14];
  const float* Wout  = (const float*)d_in[15];
  const float* bout  = (const float*)d_in[16];

  const int N = in_sizes[0] / NFEAT;
  const int E = in_sizes[2];
  float* out = (float*)d_out;

  const size_t nf = (size_t)N * NFEAT;
  float* P     = (float*)d_ws;        // 3*nf
  float* NB    = P + 3 * nf;          // nf
  float* stats = NB + nf;             // 768
  float* bn    = stats + 768;         // 768
  float* MT    = bn + 768;            // 1536
  float* cb    = MT + 1536;           // 4

  hipMemsetAsync(NB, 0, nf * sizeof(float), stream);
  hipMemsetAsync(stats, 0, 768 * sizeof(float), stream);

  const int nrb = (N + 127) / 128;
  k1_gemm<<<nrb * 3, 256, 0, stream>>>(feat, Ws, bs, Wi, bi, Wr, br, P, stats, N);
  k2_params<<<1, 256, 0, stream>>>(stats, gamma, beta, WtoI, btoI, WtoR, btoR,
                                   Wout, bout, bn, MT, cb, N);
  const long nth = (long)E * 32;
  k3_scatter<<<(int)((nth + 255) / 256), 256, 0, stream>>>(P + nf, eidx, ew, bn, NB, E);
  k4_final<<<(N + 15) / 16, 256, 0, stream>>>(P, NB, bn, MT, cb, out, N);
}

// Round 3
// 368.282 us; speedup vs baseline: 3.3888x; 3.3888x over previous
//
#include <hip/hip_runtime.h>
#include <math.h>

#define NFEAT 128
#define EPSBN 1e-5f

// ---------------------------------------------------------------------------
// K1: P_w = feature @ W_w + b_w + feature   for w in {s,i,r}
//     plus per-column sum / sumsq (for BatchNorm batch stats)
// grid = 3 * ceil(N/128) blocks, 256 threads.  bid%3 selects the weight.
// ---------------------------------------------------------------------------
__global__ __launch_bounds__(256, 2) void k1_gemm(
    const float* __restrict__ feat,
    const float* __restrict__ Ws, const float* __restrict__ bs,
    const float* __restrict__ Wi, const float* __restrict__ bi,
    const float* __restrict__ Wr, const float* __restrict__ br,
    float* __restrict__ Pout,    // 3 consecutive N x 128 matrices
    float* __restrict__ stats,   // 6*128: sum_s, ssq_s, sum_i, ssq_i, sum_r, ssq_r
    int N)
{
  const int bid = blockIdx.x;
  const int wi  = bid % 3;
  const int rb  = bid / 3;
  const int row0 = rb * 128;

  const float* W    = (wi == 0) ? Ws : ((wi == 1) ? Wi : Wr);
  const float* bias = (wi == 0) ? bs : ((wi == 1) ? bi : br);
  float* P    = Pout  + (size_t)wi * N * NFEAT;
  float* sump = stats + wi * 256;
  float* ssqp = sump + 128;

  __shared__ float Ach[128 * 32];   // 16 KB  A chunk, row-major [r][k]
  __shared__ float Wch[32 * 128];   // 16 KB  W chunk, row-major [k][c]
  __shared__ float red[16 * 128];   //  8 KB  stats reduction

  const int tid = threadIdx.x;
  const int rg = tid >> 4;          // 0..15 -> 8 rows each
  const int cg = tid & 15;          // 0..15 -> cols {4cg..4cg+3} u {64+4cg..}
  const int r0 = rg * 8;
  const int c0 = cg * 4;
  const int c1 = 64 + c0;

  float4 accA[8], accB[8];
#pragma unroll
  for (int j = 0; j < 8; j++) {
    accA[j] = make_float4(0.f, 0.f, 0.f, 0.f);
    accB[j] = make_float4(0.f, 0.f, 0.f, 0.f);
  }

  for (int kk = 0; kk < 4; kk++) {
    __syncthreads();
    // stage A chunk: Ach[r][k] = feat[row0+r][kk*32+k]
#pragma unroll
    for (int i = 0; i < 4; i++) {
      int q = i * 256 + tid;              // 0..1023 float4 slots
      int r = q >> 3;
      int k4 = (q & 7) * 4;
      int rs = row0 + r; if (rs >= N) rs = N - 1;
      *(float4*)&Ach[r * 32 + k4] =
          *(const float4*)&feat[(size_t)rs * NFEAT + kk * 32 + k4];
    }
    // stage W chunk (linear 16 KB copy)
#pragma unroll
    for (int i = 0; i < 4; i++) {
      int q = i * 256 + tid;
      *(float4*)&Wch[q * 4] = *(const float4*)&W[(size_t)kk * 4096 + q * 4];
    }
    __syncthreads();

#pragma unroll
    for (int k4 = 0; k4 < 32; k4 += 4) {
      float4 a[8];
#pragma unroll
      for (int j = 0; j < 8; j++)
        a[j] = *(float4*)&Ach[(r0 + j) * 32 + k4];
#pragma unroll
      for (int t = 0; t < 4; t++) {
        float4 w0 = *(float4*)&Wch[(k4 + t) * 128 + c0];
        float4 w1 = *(float4*)&Wch[(k4 + t) * 128 + c1];
#pragma unroll
        for (int j = 0; j < 8; j++) {
          float av = (t == 0) ? a[j].x : (t == 1) ? a[j].y : (t == 2) ? a[j].z : a[j].w;
          accA[j].x = fmaf(av, w0.x, accA[j].x);
          accA[j].y = fmaf(av, w0.y, accA[j].y);
          accA[j].z = fmaf(av, w0.z, accA[j].z);
          accA[j].w = fmaf(av, w0.w, accA[j].w);
          accB[j].x = fmaf(av, w1.x, accB[j].x);
          accB[j].y = fmaf(av, w1.y, accB[j].y);
          accB[j].z = fmaf(av, w1.z, accB[j].z);
          accB[j].w = fmaf(av, w1.w, accB[j].w);
        }
      }
    }
  }

  // epilogue: + bias + residual, store, column partial sums
  float4 b0 = *(const float4*)&bias[c0];
  float4 b1 = *(const float4*)&bias[c1];
  float4 cs0 = make_float4(0,0,0,0), cq0 = make_float4(0,0,0,0);
  float4 cs1 = make_float4(0,0,0,0), cq1 = make_float4(0,0,0,0);
#pragma unroll
  for (int j = 0; j < 8; j++) {
    int r = row0 + r0 + j;
    if (r < N) {
      float4 f0 = *(const float4*)&feat[(size_t)r * NFEAT + c0];
      float4 f1 = *(const float4*)&feat[(size_t)r * NFEAT + c1];
      float4 v0, v1;
      v0.x = accA[j].x + b0.x + f0.x;  v0.y = accA[j].y + b0.y + f0.y;
      v0.z = accA[j].z + b0.z + f0.z;  v0.w = accA[j].w + b0.w + f0.w;
      v1.x = accB[j].x + b1.x + f1.x;  v1.y = accB[j].y + b1.y + f1.y;
      v1.z = accB[j].z + b1.z + f1.z;  v1.w = accB[j].w + b1.w + f1.w;
      *(float4*)&P[(size_t)r * NFEAT + c0] = v0;
      *(float4*)&P[(size_t)r * NFEAT + c1] = v1;
      cs0.x += v0.x; cs0.y += v0.y; cs0.z += v0.z; cs0.w += v0.w;
      cs1.x += v1.x; cs1.y += v1.y; cs1.z += v1.z; cs1.w += v1.w;
      cq0.x += v0.x*v0.x; cq0.y += v0.y*v0.y; cq0.z += v0.z*v0.z; cq0.w += v0.w*v0.w;
      cq1.x += v1.x*v1.x; cq1.y += v1.y*v1.y; cq1.z += v1.z*v1.z; cq1.w += v1.w*v1.w;
    }
  }

  // block-level column reduce, then one atomic per column per block
  *(float4*)&red[rg * 128 + c0] = cs0;
  *(float4*)&red[rg * 128 + c1] = cs1;
  __syncthreads();
  if (tid < 128) {
    float s = 0.f;
#pragma unroll
    for (int g = 0; g < 16; g++) s += red[g * 128 + tid];
    unsafeAtomicAdd(&sump[tid], s);
  }
  __syncthreads();
  *(float4*)&red[rg * 128 + c0] = cq0;
  *(float4*)&red[rg * 128 + c1] = cq1;
  __syncthreads();
  if (tid < 128) {
    float s = 0.f;
#pragma unroll
    for (int g = 0; g < 16; g++) s += red[g * 128 + tid];
    unsafeAtomicAdd(&ssqp[tid], s);
  }
}

// ---------------------------------------------------------------------------
// K2: one block. BN scale/shift per column for the 3 matrices, and fold the
// entire linear back-half into 4 F x 3 matrices + 3-vector bias:
//   logits = S@M1 + I@M3 + R@M4 + NB@M2 + cb
// MT layout: MT[cl*512 + part*128 + k], part: 0=S 1=I 2=R 3=NB
// ---------------------------------------------------------------------------
__global__ void k2_params(
    const float* __restrict__ stats,
    const float* __restrict__ gamma, const float* __restrict__ beta,
    const float* __restrict__ WtoI, const float* __restrict__ btoI,
    const float* __restrict__ WtoR, const float* __restrict__ btoR,
    const float* __restrict__ Wout, const float* __restrict__ bout,
    float* __restrict__ bn,   // 6*128: [w]{a[128], b[128]}
    float* __restrict__ MT,   // 3*512
    float* __restrict__ cb,   // 4
    int N)
{
  const int tid = threadIdx.x;
  const float invN = 1.0f / (float)N;

  for (int t = tid; t < 384; t += 256) {
    int w = t >> 7, c = t & 127;
    float sm = stats[w * 256 + c];
    float sq = stats[w * 256 + 128 + c];
    float m = sm * invN;
    float v = sq * invN - m * m;
    float rinv = rsqrtf(v + EPSBN);
    float a = gamma[c] * rinv;
    bn[w * 256 + c] = a;
    bn[w * 256 + 128 + c] = beta[c] - m * a;
  }

  for (int t = tid; t < 1536; t += 256) {
    int cl = t / 512;
    int idx = t - cl * 512;
    int part = idx >> 7, k = idx & 127;
    float val;
    if (part == 0) {            // S: Wo1 + WtoI_top @ (Wo2-Wo1)
      float s = Wout[k * 3 + cl];
      for (int f = 0; f < 128; f++)
        s = fmaf(WtoI[k * 128 + f],
                 Wout[(128 + f) * 3 + cl] - Wout[f * 3 + cl], s);
      val = s;
    } else if (part == 1) {     // I: Wo2 + WtoR @ (Wo3-Wo2)
      float s = Wout[(128 + k) * 3 + cl];
      for (int f = 0; f < 128; f++)
        s = fmaf(WtoR[k * 128 + f],
                 Wout[(256 + f) * 3 + cl] - Wout[(128 + f) * 3 + cl], s);
      val = s;
    } else if (part == 2) {     // R: Wo3
      val = Wout[(256 + k) * 3 + cl];
    } else {                    // NB: WtoI_bot @ (Wo2-Wo1)
      float s = 0.f;
      for (int f = 0; f < 128; f++)
        s = fmaf(WtoI[(128 + k) * 128 + f],
                 Wout[(128 + f) * 3 + cl] - Wout[f * 3 + cl], s);
      val = s;
    }
    MT[cl * 512 + idx] = val;
  }

  if (tid < 3) {
    float s = bout[tid];
    for (int f = 0; f < 128; f++) {
      s = fmaf(btoI[f], Wout[(128 + f) * 3 + tid] - Wout[f * 3 + tid], s);
      s = fmaf(btoR[f], Wout[(256 + f) * 3 + tid] - Wout[(128 + f) * 3 + tid], s);
    }
    cb[tid] = s;
  }
}

// ---------------------------------------------------------------------------
// K3 pipeline: CSR build by dst, then atomic-free gather.
// ---------------------------------------------------------------------------
__global__ __launch_bounds__(256) void k_hist(
    const int* __restrict__ eidx, int* __restrict__ deg, int E)
{
  int e = blockIdx.x * 256 + threadIdx.x;
  if (e < E) atomicAdd(&deg[eidx[E + e]], 1);
}

// block-level exclusive scan over 1024-element tiles
__global__ __launch_bounds__(256) void k_scan1(
    const int* __restrict__ deg, int* __restrict__ part,
    int* __restrict__ bsum, int N)
{
  __shared__ int sc[256];
  const int tid = threadIdx.x;
  const int base = blockIdx.x * 1024 + tid * 4;
  int v[4];
#pragma unroll
  for (int j = 0; j < 4; j++) {
    int i = base + j;
    v[j] = (i < N) ? deg[i] : 0;
  }
  int tsum = v[0] + v[1] + v[2] + v[3];
  sc[tid] = tsum;
  __syncthreads();
  for (int off = 1; off < 256; off <<= 1) {
    int x = (tid >= off) ? sc[tid - off] : 0;
    __syncthreads();
    sc[tid] += x;
    __syncthreads();
  }
  if (tid == 255) bsum[blockIdx.x] = sc[255];
  int run = sc[tid] - tsum;   // exclusive prefix of this thread
#pragma unroll
  for (int j = 0; j < 4; j++) {
    int i = base + j;
    if (i < N) part[i] = run;
    run += v[j];
  }
}

// single block: exclusive scan of per-block sums (nblk <= 256)
__global__ __launch_bounds__(256) void k_scan2(int* __restrict__ bsum, int nblk)
{
  __shared__ int sc[256];
  const int tid = threadIdx.x;
  int v = (tid < nblk) ? bsum[tid] : 0;
  sc[tid] = v;
  __syncthreads();
  for (int off = 1; off < 256; off <<= 1) {
    int x = (tid >= off) ? sc[tid - off] : 0;
    __syncthreads();
    sc[tid] += x;
    __syncthreads();
  }
  if (tid < nblk) bsum[tid] = sc[tid] - v;
}

__global__ __launch_bounds__(256) void k_scan3(
    const int* __restrict__ part, const int* __restrict__ bsum,
    int* __restrict__ rowstart, int* __restrict__ cursor, int N)
{
  int i = blockIdx.x * 256 + threadIdx.x;
  if (i < N) {
    int v = part[i] + bsum[i >> 10];
    rowstart[i] = v;
    cursor[i] = v;
  }
}

// scatter (src, w) into dst-sorted slots
__global__ __launch_bounds__(256) void k_build(
    const int* __restrict__ eidx, const float* __restrict__ ew,
    int* __restrict__ cursor, int* __restrict__ srcb, float* __restrict__ wb,
    int E)
{
  int e = blockIdx.x * 256 + threadIdx.x;
  if (e < E) {
    int dst = eidx[E + e];
    int slot = atomicAdd(&cursor[dst], 1);
    srcb[slot] = eidx[e];
    wb[slot] = ew[e];
  }
}

// gather: NB[r] = sum over edges of relu(bn_i(Pi[src])) * w.  32 lanes/row.
__global__ __launch_bounds__(256) void k_gather(
    const float* __restrict__ Pi,
    const int* __restrict__ rowstart, const int* __restrict__ deg,
    const int* __restrict__ srcb, const float* __restrict__ wb,
    const float* __restrict__ bn,
    float* __restrict__ NB, int N)
{
  int r = blockIdx.x * 8 + (threadIdx.x >> 5);
  if (r >= N) return;
  const int c = (threadIdx.x & 31) * 4;

  const int rs = rowstart[r];
  const int d  = deg[r];
  float4 a = *(const float4*)&bn[256 + c];        // i-matrix scale
  float4 b = *(const float4*)&bn[256 + 128 + c];  // i-matrix shift
  float4 acc = make_float4(0.f, 0.f, 0.f, 0.f);

  for (int s = 0; s < d; s++) {
    int src = srcb[rs + s];       // wave-uniform per group -> broadcast
    float w = wb[rs + s];
    float4 x = *(const float4*)&Pi[(size_t)src * NFEAT + c];
    acc.x += fmaxf(fmaf(a.x, x.x, b.x), 0.f) * w;
    acc.y += fmaxf(fmaf(a.y, x.y, b.y), 0.f) * w;
    acc.z += fmaxf(fmaf(a.z, x.z, b.z), 0.f) * w;
    acc.w += fmaxf(fmaf(a.w, x.w, b.w), 0.f) * w;
  }
  *(float4*)&NB[(size_t)r * NFEAT + c] = acc;
}

// ---------------------------------------------------------------------------
// K4: per-row fused BN+ReLU, 512x3 dot with folded MT, softmax.
// 16 lanes per row (4 matrix-parts x 4 segments), 16 rows per 256-thr block.
// ---------------------------------------------------------------------------
__global__ __launch_bounds__(256) void k4_final(
    const float* __restrict__ P,   // 3 consecutive N x 128
    const float* __restrict__ NB,
    const float* __restrict__ bn,
    const float* __restrict__ MT,
    const float* __restrict__ cb,
    float* __restrict__ out, int N)
{
  __shared__ float MTs[1536];
  __shared__ float bns[768];
  const int tid = threadIdx.x;
  for (int i = tid; i < 1536; i += 256) MTs[i] = MT[i];
  for (int i = tid; i < 768; i += 256) bns[i] = bn[i];
  __syncthreads();

  const int row0 = blockIdx.x * 16 + (tid >> 4);
  const int row  = (row0 < N) ? row0 : (N - 1);
  const int p   = tid & 15;
  const int mp  = p >> 2;       // 0=S 1=I 2=R 3=NB
  const int seg = p & 3;        // 32-float segment

  const float* xsrc = (mp < 3)
      ? (P + ((size_t)mp * N + row) * NFEAT + seg * 32)
      : (NB + (size_t)row * NFEAT + seg * 32);

  float pa0 = 0.f, pa1 = 0.f, pa2 = 0.f;
#pragma unroll
  for (int i = 0; i < 8; i++) {
    float4 x = *(const float4*)&xsrc[i * 4];
    if (mp < 3) {
      int c = seg * 32 + i * 4;
      float4 a = *(float4*)&bns[mp * 256 + c];
      float4 b = *(float4*)&bns[mp * 256 + 128 + c];
      x.x = fmaxf(fmaf(a.x, x.x, b.x), 0.f);
      x.y = fmaxf(fmaf(a.y, x.y, b.y), 0.f);
      x.z = fmaxf(fmaf(a.z, x.z, b.z), 0.f);
      x.w = fmaxf(fmaf(a.w, x.w, b.w), 0.f);
    }
    int mo = mp * 128 + seg * 32 + i * 4;
    {
      float4 m = *(float4*)&MTs[0 * 512 + mo];
      pa0 += x.x * m.x + x.y * m.y + x.z * m.z + x.w * m.w;
    }
    {
      float4 m = *(float4*)&MTs[1 * 512 + mo];
      pa1 += x.x * m.x + x.y * m.y + x.z * m.z + x.w * m.w;
    }
    {
      float4 m = *(float4*)&MTs[2 * 512 + mo];
      pa2 += x.x * m.x + x.y * m.y + x.z * m.z + x.w * m.w;
    }
  }
#pragma unroll
  for (int off = 1; off < 16; off <<= 1) {
    pa0 += __shfl_xor(pa0, off);
    pa1 += __shfl_xor(pa1, off);
    pa2 += __shfl_xor(pa2, off);
  }
  if (p == 0 && row0 < N) {
    float l0 = pa0 + cb[0], l1 = pa1 + cb[1], l2 = pa2 + cb[2];
    float mx = fmaxf(l0, fmaxf(l1, l2));
    float e0 = expf(l0 - mx), e1 = expf(l1 - mx), e2 = expf(l2 - mx);
    float inv = 1.f / (e0 + e1 + e2);
    out[(size_t)row0 * 3 + 0] = e0 * inv;
    out[(size_t)row0 * 3 + 1] = e1 * inv;
    out[(size_t)row0 * 3 + 2] = e2 * inv;
  }
}

// ---------------------------------------------------------------------------
extern "C" void kernel_launch(void* const* d_in, const int* in_sizes, int n_in,
                              void* d_out, int out_size, void* d_ws, size_t ws_size,
                              hipStream_t stream)
{
  const float* feat  = (const float*)d_in[0];
  const int*   eidx  = (const int*)  d_in[1];
  const float* ew    = (const float*)d_in[2];
  const float* Ws    = (const float*)d_in[3];
  const float* bs    = (const float*)d_in[4];
  const float* Wi    = (const float*)d_in[5];
  const float* bi    = (const float*)d_in[6];
  const float* Wr    = (const float*)d_in[7];
  const float* br    = (const float*)d_in[8];
  const float* gamma = (const float*)d_in[9];
  const float* beta  = (const float*)d_in[10];
  const float* WtoI  = (const float*)d_in[11];
  const float* btoI  = (const float*)d_in[12];
  const float* WtoR  = (const float*)d_in[13];
  const float* btoR  = (const float*)d_in[14];
  const float* Wout  = (const float*)d_in[15];
  const float* bout  = (const float*)d_in[16];

  const int N = in_sizes[0] / NFEAT;
  const int E = in_sizes[2];
  float* out = (float*)d_out;

  const size_t nf = (size_t)N * NFEAT;
  float* P     = (float*)d_ws;        // 3*nf
  float* NB    = P + 3 * nf;          // nf
  float* stats = NB + nf;             // 768
  float* bn    = stats + 768;         // 768
  float* MT    = bn + 768;            // 1536
  float* cb    = MT + 1536;           // 4
  int*   deg      = (int*)(cb + 4);   // N
  int*   rowstart = deg + N;          // N
  int*   cursor   = rowstart + N;     // N
  int*   part     = cursor + N;       // N
  int*   bsum     = part + N;         // 256
  int*   srcb     = bsum + 256;       // E
  float* wb       = (float*)(srcb + E); // E

  hipMemsetAsync(stats, 0, 768 * sizeof(float), stream);
  hipMemsetAsync(deg, 0, (size_t)N * sizeof(int), stream);

  const int nrb = (N + 127) / 128;
  const int nscan = (N + 1023) / 1024;          // 98 for N=100000 (<=256)
  const int nb256 = (N + 255) / 256;
  const int eb256 = (E + 255) / 256;

  k1_gemm<<<nrb * 3, 256, 0, stream>>>(feat, Ws, bs, Wi, bi, Wr, br, P, stats, N);
  k2_params<<<1, 256, 0, stream>>>(stats, gamma, beta, WtoI, btoI, WtoR, btoR,
                                   Wout, bout, bn, MT, cb, N);

  // CSR build (independent of k1/k2 results)
  k_hist <<<eb256, 256, 0, stream>>>(eidx, deg, E);
  k_scan1<<<nscan, 256, 0, stream>>>(deg, part, bsum, N);
  k_scan2<<<1, 256, 0, stream>>>(bsum, nscan);
  k_scan3<<<nb256, 256, 0, stream>>>(part, bsum, rowstart, cursor, N);
  k_build<<<eb256, 256, 0, stream>>>(eidx, ew, cursor, srcb, wb, E);

  k_gather<<<(N + 7) / 8, 256, 0, stream>>>(P + nf, rowstart, deg, srcb, wb,
                                            bn, NB, N);
  k4_final<<<(N + 15) / 16, 256, 0, stream>>>(P, NB, bn, MT, cb, out, N);
}

// Round 4
// 350.700 us; speedup vs baseline: 3.5587x; 1.0501x over previous
//
#include <hip/hip_runtime.h>
#include <math.h>

#define NFEAT 128
#define EPSBN 1e-5f
#define LDA 136   // bf16 elems per LDS row: 128 + 8 pad (272 B, 16B-aligned)

typedef __attribute__((ext_vector_type(8))) short short8;
typedef __attribute__((ext_vector_type(4))) float f32x4;

__device__ __forceinline__ unsigned short f2bf(float x) {
  union { float f; unsigned u; } v; v.f = x;
  unsigned r = v.u + 0x7FFF + ((v.u >> 16) & 1);   // RNE
  return (unsigned short)(r >> 16);
}
__device__ __forceinline__ float bf2f(unsigned short h) {
  union { unsigned u; float f; } v; v.u = (unsigned)h << 16;
  return v.f;
}

// ---------------------------------------------------------------------------
// K1 (MFMA, split-bf16): P_w = feature @ W_w + b_w + feature  for w in {s,i,r}
// plus per-column sum/sumsq.  A = Ah+Al, W = Wh+Wl (bf16 each);
// P ≈ Ah·Wh + Al·Wh + Ah·Wl  (fp32 MFMA accum; dropped Al·Wl ~ 2^-18 rel).
// grid = ceil(N/64), 512 threads = 8 waves; wave wv owns 64 rows x cols
// [wv*16, wv*16+16) for all 3 matrices.
// ---------------------------------------------------------------------------
__global__ __launch_bounds__(512, 2) void k1_gemm(
    const float* __restrict__ feat,
    const float* __restrict__ Ws, const float* __restrict__ bs,
    const float* __restrict__ Wi, const float* __restrict__ bi,
    const float* __restrict__ Wr, const float* __restrict__ br,
    float* __restrict__ Pout,    // 3 consecutive N x 128 matrices
    float* __restrict__ stats,   // 6*128
    int N)
{
  __shared__ short Ah[64 * LDA];
  __shared__ short Al[64 * LDA];

  const int tid  = threadIdx.x;
  const int row0 = blockIdx.x * 64;
  const int lane = tid & 63;
  const int wv   = tid >> 6;

  const float* Wm[3] = {Ws, Wi, Wr};
  const float* Bm[3] = {bs, bi, br};

  const int cw   = wv * 16;
  const int colb = cw + (lane & 15);
  const int krow = (lane >> 4) * 8;   // k-offset of this lane's 8 elements

  // ---- B fragments (hi/lo), 3 mats x 4 k-frags, loaded once (L2-resident W)
  short8 bh[3][4], bl[3][4];
#pragma unroll
  for (int m = 0; m < 3; m++) {
#pragma unroll
    for (int kf = 0; kf < 4; kf++) {
      const float* wp = Wm[m] + (size_t)(kf * 32 + krow) * NFEAT + colb;
#pragma unroll
      for (int j = 0; j < 8; j++) {
        float w = wp[j * NFEAT];
        unsigned short h = f2bf(w);
        bh[m][kf][j] = (short)h;
        bl[m][kf][j] = (short)f2bf(w - bf2f(h));
      }
    }
  }

  // ---- stage A tile (64 rows x 128), split hi/lo into LDS
  {
    int r = tid >> 3, o = tid & 7;          // 8 threads per row, 16 f32 each
    int gr = row0 + r; if (gr >= N) gr = N - 1;
    const float4* s4 = (const float4*)(feat + (size_t)gr * NFEAT + o * 16);
    short hbuf[16], lbuf[16];
#pragma unroll
    for (int q = 0; q < 4; q++) {
      float4 f = s4[q];
      float xs[4] = {f.x, f.y, f.z, f.w};
#pragma unroll
      for (int c = 0; c < 4; c++) {
        unsigned short h = f2bf(xs[c]);
        hbuf[q * 4 + c] = (short)h;
        lbuf[q * 4 + c] = (short)f2bf(xs[c] - bf2f(h));
      }
    }
    short* dh = &Ah[r * LDA + o * 16];
    short* dl = &Al[r * LDA + o * 16];
    *(short8*)(dh)     = *(short8*)(hbuf);
    *(short8*)(dh + 8) = *(short8*)(hbuf + 8);
    *(short8*)(dl)     = *(short8*)(lbuf);
    *(short8*)(dl + 8) = *(short8*)(lbuf + 8);
  }
  __syncthreads();

  // ---- MFMA main loop: 4 k-frags x (3 mats x 4 row-frags) x 3 products
  f32x4 acc[3][4];
#pragma unroll
  for (int m = 0; m < 3; m++)
#pragma unroll
    for (int rf = 0; rf < 4; rf++)
      acc[m][rf] = (f32x4){0.f, 0.f, 0.f, 0.f};

#pragma unroll
  for (int kf = 0; kf < 4; kf++) {
    short8 ah[4], al[4];
#pragma unroll
    for (int rf = 0; rf < 4; rf++) {
      int off = (rf * 16 + (lane & 15)) * LDA + kf * 32 + krow;
      ah[rf] = *(const short8*)&Ah[off];
      al[rf] = *(const short8*)&Al[off];
    }
#pragma unroll
    for (int m = 0; m < 3; m++) {
#pragma unroll
      for (int rf = 0; rf < 4; rf++) {
        acc[m][rf] = __builtin_amdgcn_mfma_f32_16x16x32_bf16(
            ah[rf], bh[m][kf], acc[m][rf], 0, 0, 0);
        acc[m][rf] = __builtin_amdgcn_mfma_f32_16x16x32_bf16(
            al[rf], bh[m][kf], acc[m][rf], 0, 0, 0);
        acc[m][rf] = __builtin_amdgcn_mfma_f32_16x16x32_bf16(
            ah[rf], bl[m][kf], acc[m][rf], 0, 0, 0);
      }
    }
  }

  // ---- epilogue: + bias + residual, store P (f32), stats via shfl+atomics
  float bias[3] = {Bm[0][colb], Bm[1][colb], Bm[2][colb]};
  float ssum[3] = {0.f, 0.f, 0.f}, sq[3] = {0.f, 0.f, 0.f};
  const size_t nf = (size_t)N * NFEAT;
#pragma unroll
  for (int rf = 0; rf < 4; rf++) {
    int rb = row0 + rf * 16 + ((lane >> 4) << 2);
    float res[4]; bool ok[4];
#pragma unroll
    for (int g = 0; g < 4; g++) {
      ok[g] = (rb + g) < N;
      res[g] = ok[g] ? feat[(size_t)(rb + g) * NFEAT + colb] : 0.f;
    }
#pragma unroll
    for (int m = 0; m < 3; m++) {
#pragma unroll
      for (int g = 0; g < 4; g++) {
        float v = acc[m][rf][g] + bias[m] + res[g];
        if (ok[g]) {
          Pout[(size_t)m * nf + (size_t)(rb + g) * NFEAT + colb] = v;
          ssum[m] += v;
          sq[m]   += v * v;
        }
      }
    }
  }
#pragma unroll
  for (int m = 0; m < 3; m++) {
    float s = ssum[m], q = sq[m];
    s += __shfl_xor(s, 16); s += __shfl_xor(s, 32);
    q += __shfl_xor(q, 16); q += __shfl_xor(q, 32);
    if ((lane >> 4) == 0) {
      unsafeAtomicAdd(&stats[m * 256 + colb], s);
      unsafeAtomicAdd(&stats[m * 256 + 128 + colb], q);
    }
  }
}

// ---------------------------------------------------------------------------
// K2: one block. BN scale/shift per column for the 3 matrices, and fold the
// entire linear back-half into 4 F x 3 matrices + 3-vector bias:
//   logits = S@M1 + I@M3 + R@M4 + NB@M2 + cb
// MT layout: MT[cl*512 + part*128 + k], part: 0=S 1=I 2=R 3=NB
// ---------------------------------------------------------------------------
__global__ void k2_params(
    const float* __restrict__ stats,
    const float* __restrict__ gamma, const float* __restrict__ beta,
    const float* __restrict__ WtoI, const float* __restrict__ btoI,
    const float* __restrict__ WtoR, const float* __restrict__ btoR,
    const float* __restrict__ Wout, const float* __restrict__ bout,
    float* __restrict__ bn,   // 6*128: [w]{a[128], b[128]}
    float* __restrict__ MT,   // 3*512
    float* __restrict__ cb,   // 4
    int N)
{
  const int tid = threadIdx.x;
  const float invN = 1.0f / (float)N;

  for (int t = tid; t < 384; t += 256) {
    int w = t >> 7, c = t & 127;
    float sm = stats[w * 256 + c];
    float sq = stats[w * 256 + 128 + c];
    float m = sm * invN;
    float v = sq * invN - m * m;
    float rinv = rsqrtf(v + EPSBN);
    float a = gamma[c] * rinv;
    bn[w * 256 + c] = a;
    bn[w * 256 + 128 + c] = beta[c] - m * a;
  }

  for (int t = tid; t < 1536; t += 256) {
    int cl = t / 512;
    int idx = t - cl * 512;
    int part = idx >> 7, k = idx & 127;
    float val;
    if (part == 0) {            // S: Wo1 + WtoI_top @ (Wo2-Wo1)
      float s = Wout[k * 3 + cl];
      for (int f = 0; f < 128; f++)
        s = fmaf(WtoI[k * 128 + f],
                 Wout[(128 + f) * 3 + cl] - Wout[f * 3 + cl], s);
      val = s;
    } else if (part == 1) {     // I: Wo2 + WtoR @ (Wo3-Wo2)
      float s = Wout[(128 + k) * 3 + cl];
      for (int f = 0; f < 128; f++)
        s = fmaf(WtoR[k * 128 + f],
                 Wout[(256 + f) * 3 + cl] - Wout[(128 + f) * 3 + cl], s);
      val = s;
    } else if (part == 2) {     // R: Wo3
      val = Wout[(256 + k) * 3 + cl];
    } else {                    // NB: WtoI_bot @ (Wo2-Wo1)
      float s = 0.f;
      for (int f = 0; f < 128; f++)
        s = fmaf(WtoI[(128 + k) * 128 + f],
                 Wout[(128 + f) * 3 + cl] - Wout[f * 3 + cl], s);
      val = s;
    }
    MT[cl * 512 + idx] = val;
  }

  if (tid < 3) {
    float s = bout[tid];
    for (int f = 0; f < 128; f++) {
      s = fmaf(btoI[f], Wout[(128 + f) * 3 + tid] - Wout[f * 3 + tid], s);
      s = fmaf(btoR[f], Wout[(256 + f) * 3 + tid] - Wout[(128 + f) * 3 + tid], s);
    }
    cb[tid] = s;
  }
}

// ---------------------------------------------------------------------------
// K3 pipeline: CSR build by dst, then atomic-free gather.
// ---------------------------------------------------------------------------
__global__ __launch_bounds__(256) void k_hist(
    const int* __restrict__ eidx, int* __restrict__ deg, int E)
{
  int e = blockIdx.x * 256 + threadIdx.x;
  if (e < E) atomicAdd(&deg[eidx[E + e]], 1);
}

// block-level exclusive scan over 1024-element tiles
__global__ __launch_bounds__(256) void k_scan1(
    const int* __restrict__ deg, int* __restrict__ part,
    int* __restrict__ bsum, int N)
{
  __shared__ int sc[256];
  const int tid = threadIdx.x;
  const int base = blockIdx.x * 1024 + tid * 4;
  int v[4];
#pragma unroll
  for (int j = 0; j < 4; j++) {
    int i = base + j;
    v[j] = (i < N) ? deg[i] : 0;
  }
  int tsum = v[0] + v[1] + v[2] + v[3];
  sc[tid] = tsum;
  __syncthreads();
  for (int off = 1; off < 256; off <<= 1) {
    int x = (tid >= off) ? sc[tid - off] : 0;
    __syncthreads();
    sc[tid] += x;
    __syncthreads();
  }
  if (tid == 255) bsum[blockIdx.x] = sc[255];
  int run = sc[tid] - tsum;   // exclusive prefix of this thread
#pragma unroll
  for (int j = 0; j < 4; j++) {
    int i = base + j;
    if (i < N) part[i] = run;
    run += v[j];
  }
}

// single block: exclusive scan of per-block sums (nblk <= 256)
__global__ __launch_bounds__(256) void k_scan2(int* __restrict__ bsum, int nblk)
{
  __shared__ int sc[256];
  const int tid = threadIdx.x;
  int v = (tid < nblk) ? bsum[tid] : 0;
  sc[tid] = v;
  __syncthreads();
  for (int off = 1; off < 256; off <<= 1) {
    int x = (tid >= off) ? sc[tid - off] : 0;
    __syncthreads();
    sc[tid] += x;
    __syncthreads();
  }
  if (tid < nblk) bsum[tid] = sc[tid] - v;
}

__global__ __launch_bounds__(256) void k_scan3(
    const int* __restrict__ part, const int* __restrict__ bsum,
    int* __restrict__ rowstart, int* __restrict__ cursor, int N)
{
  int i = blockIdx.x * 256 + threadIdx.x;
  if (i < N) {
    int v = part[i] + bsum[i >> 10];
    rowstart[i] = v;
    cursor[i] = v;
  }
}

// scatter (src, w) into dst-sorted slots
__global__ __launch_bounds__(256) void k_build(
    const int* __restrict__ eidx, const float* __restrict__ ew,
    int* __restrict__ cursor, int* __restrict__ srcb, float* __restrict__ wb,
    int E)
{
  int e = blockIdx.x * 256 + threadIdx.x;
  if (e < E) {
    int dst = eidx[E + e];
    int slot = atomicAdd(&cursor[dst], 1);
    srcb[slot] = eidx[e];
    wb[slot] = ew[e];
  }
}

// gather: NB[r] = sum over edges of relu(bn_i(Pi[src])) * w.  32 lanes/row.
__global__ __launch_bounds__(256) void k_gather(
    const float* __restrict__ Pi,
    const int* __restrict__ rowstart, const int* __restrict__ deg,
    const int* __restrict__ srcb, const float* __restrict__ wb,
    const float* __restrict__ bn,
    float* __restrict__ NB, int N)
{
  int r = blockIdx.x * 8 + (threadIdx.x >> 5);
  if (r >= N) return;
  const int c = (threadIdx.x & 31) * 4;

  const int rs = rowstart[r];
  const int d  = deg[r];
  float4 a = *(const float4*)&bn[256 + c];        // i-matrix scale
  float4 b = *(const float4*)&bn[256 + 128 + c];  // i-matrix shift
  float4 acc = make_float4(0.f, 0.f, 0.f, 0.f);

  for (int s = 0; s < d; s++) {
    int src = srcb[rs + s];       // wave-uniform per group -> broadcast
    float w = wb[rs + s];
    float4 x = *(const float4*)&Pi[(size_t)src * NFEAT + c];
    acc.x += fmaxf(fmaf(a.x, x.x, b.x), 0.f) * w;
    acc.y += fmaxf(fmaf(a.y, x.y, b.y), 0.f) * w;
    acc.z += fmaxf(fmaf(a.z, x.z, b.z), 0.f) * w;
    acc.w += fmaxf(fmaf(a.w, x.w, b.w), 0.f) * w;
  }
  *(float4*)&NB[(size_t)r * NFEAT + c] = acc;
}

// ---------------------------------------------------------------------------
// K4: per-row fused BN+ReLU, 512x3 dot with folded MT, softmax.
// 16 lanes per row (4 matrix-parts x 4 segments), 16 rows per 256-thr block.
// ---------------------------------------------------------------------------
__global__ __launch_bounds__(256) void k4_final(
    const float* __restrict__ P,   // 3 consecutive N x 128
    const float* __restrict__ NB,
    const float* __restrict__ bn,
    const float* __restrict__ MT,
    const float* __restrict__ cb,
    float* __restrict__ out, int N)
{
  __shared__ float MTs[1536];
  __shared__ float bns[768];
  const int tid = threadIdx.x;
  for (int i = tid; i < 1536; i += 256) MTs[i] = MT[i];
  for (int i = tid; i < 768; i += 256) bns[i] = bn[i];
  __syncthreads();

  const int row0 = blockIdx.x * 16 + (tid >> 4);
  const int row  = (row0 < N) ? row0 : (N - 1);
  const int p   = tid & 15;
  const int mp  = p >> 2;       // 0=S 1=I 2=R 3=NB
  const int seg = p & 3;        // 32-float segment

  const float* xsrc = (mp < 3)
      ? (P + ((size_t)mp * N + row) * NFEAT + seg * 32)
      : (NB + (size_t)row * NFEAT + seg * 32);

  float pa0 = 0.f, pa1 = 0.f, pa2 = 0.f;
#pragma unroll
  for (int i = 0; i < 8; i++) {
    float4 x = *(const float4*)&xsrc[i * 4];
    if (mp < 3) {
      int c = seg * 32 + i * 4;
      float4 a = *(float4*)&bns[mp * 256 + c];
      float4 b = *(float4*)&bns[mp * 256 + 128 + c];
      x.x = fmaxf(fmaf(a.x, x.x, b.x), 0.f);
      x.y = fmaxf(fmaf(a.y, x.y, b.y), 0.f);
      x.z = fmaxf(fmaf(a.z, x.z, b.z), 0.f);
      x.w = fmaxf(fmaf(a.w, x.w, b.w), 0.f);
    }
    int mo = mp * 128 + seg * 32 + i * 4;
    {
      float4 m = *(float4*)&MTs[0 * 512 + mo];
      pa0 += x.x * m.x + x.y * m.y + x.z * m.z + x.w * m.w;
    }
    {
      float4 m = *(float4*)&MTs[1 * 512 + mo];
      pa1 += x.x * m.x + x.y * m.y + x.z * m.z + x.w * m.w;
    }
    {
      float4 m = *(float4*)&MTs[2 * 512 + mo];
      pa2 += x.x * m.x + x.y * m.y + x.z * m.z + x.w * m.w;
    }
  }
#pragma unroll
  for (int off = 1; off < 16; off <<= 1) {
    pa0 += __shfl_xor(pa0, off);
    pa1 += __shfl_xor(pa1, off);
    pa2 += __shfl_xor(pa2, off);
  }
  if (p == 0 && row0 < N) {
    float l0 = pa0 + cb[0], l1 = pa1 + cb[1], l2 = pa2 + cb[2];
    float mx = fmaxf(l0, fmaxf(l1, l2));
    float e0 = expf(l0 - mx), e1 = expf(l1 - mx), e2 = expf(l2 - mx);
    float inv = 1.f / (e0 + e1 + e2);
    out[(size_t)row0 * 3 + 0] = e0 * inv;
    out[(size_t)row0 * 3 + 1] = e1 * inv;
    out[(size_t)row0 * 3 + 2] = e2 * inv;
  }
}

// ---------------------------------------------------------------------------
extern "C" void kernel_launch(void* const* d_in, const int* in_sizes, int n_in,
                              void* d_out, int out_size, void* d_ws, size_t ws_size,
                              hipStream_t stream)
{
  const float* feat  = (const float*)d_in[0];
  const int*   eidx  = (const int*)  d_in[1];
  const float* ew    = (const float*)d_in[2];
  const float* Ws    = (const float*)d_in[3];
  const float* bs    = (const float*)d_in[4];
  const float* Wi    = (const float*)d_in[5];
  const float* bi    = (const float*)d_in[6];
  const float* Wr    = (const float*)d_in[7];
  const float* br    = (const float*)d_in[8];
  const float* gamma = (const float*)d_in[9];
  const float* beta  = (const float*)d_in[10];
  const float* WtoI  = (const float*)d_in[11];
  const float* btoI  = (const float*)d_in[12];
  const float* WtoR  = (const float*)d_in[13];
  const float* btoR  = (const float*)d_in[14];
  const float* Wout  = (const float*)d_in[15];
  const float* bout  = (const float*)d_in[16];

  const int N = in_sizes[0] / NFEAT;
  const int E = in_sizes[2];
  float* out = (float*)d_out;

  const size_t nf = (size_t)N * NFEAT;
  float* P     = (float*)d_ws;        // 3*nf
  float* NB    = P + 3 * nf;          // nf
  float* stats = NB + nf;             // 768
  float* bn    = stats + 768;         // 768
  float* MT    = bn + 768;            // 1536
  float* cb    = MT + 1536;           // 4
  int*   deg      = (int*)(cb + 4);   // N
  int*   rowstart = deg + N;          // N
  int*   cursor   = rowstart + N;     // N
  int*   part     = cursor + N;       // N
  int*   bsum     = part + N;         // 256
  int*   srcb     = bsum + 256;       // E
  float* wb       = (float*)(srcb + E); // E

  hipMemsetAsync(stats, 0, 768 * sizeof(float), stream);
  hipMemsetAsync(deg, 0, (size_t)N * sizeof(int), stream);

  const int nrb1 = (N + 63) / 64;
  const int nscan = (N + 1023) / 1024;          // 98 for N=100000 (<=256)
  const int nb256 = (N + 255) / 256;
  const int eb256 = (E + 255) / 256;

  k1_gemm<<<nrb1, 512, 0, stream>>>(feat, Ws, bs, Wi, bi, Wr, br, P, stats, N);
  k2_params<<<1, 256, 0, stream>>>(stats, gamma, beta, WtoI, btoI, WtoR, btoR,
                                   Wout, bout, bn, MT, cb, N);

  // CSR build (independent of k1/k2 results)
  k_hist <<<eb256, 256, 0, stream>>>(eidx, deg, E);
  k_scan1<<<nscan, 256, 0, stream>>>(deg, part, bsum, N);
  k_scan2<<<1, 256, 0, stream>>>(bsum, nscan);
  k_scan3<<<nb256, 256, 0, stream>>>(part, bsum, rowstart, cursor, N);
  k_build<<<eb256, 256, 0, stream>>>(eidx, ew, cursor, srcb, wb, E);

  k_gather<<<(N + 7) / 8, 256, 0, stream>>>(P + nf, rowstart, deg, srcb, wb,
                                            bn, NB, N);
  k4_final<<<(N + 15) / 16, 256, 0, stream>>>(P, NB, bn, MT, cb, out, N);
}

// Round 5
// 275.408 us; speedup vs baseline: 4.5316x; 1.2734x over previous
//
#include <hip/hip_runtime.h>
#include <math.h>

#define NFEAT 128
#define EPSBN 1e-5f
#define LDA 136   // bf16 elems per LDS row: 128 + 8 pad (272 B, 16B-aligned)

typedef __attribute__((ext_vector_type(8))) short short8;
typedef __attribute__((ext_vector_type(4))) float f32x4;

__device__ __forceinline__ unsigned short f2bf(float x) {
  union { float f; unsigned u; } v; v.f = x;
  unsigned r = v.u + 0x7FFF + ((v.u >> 16) & 1);   // RNE
  return (unsigned short)(r >> 16);
}
__device__ __forceinline__ float bf2f(unsigned short h) {
  union { unsigned u; float f; } v; v.u = (unsigned)h << 16;
  return v.f;
}

// ---------------------------------------------------------------------------
// K0: split Ws/Wi/Wr into bf16 hi/lo planes, stored in MFMA B-fragment order:
//   Whi[((m*4+kf)*4+kg)*1024 + c*8 + j] = bf16( W_m[(kf*32+kg*8+j)*128 + c] )
// so k1 loads a fragment as one coalesced short8.
// ---------------------------------------------------------------------------
__global__ __launch_bounds__(256) void k0_wsplit(
    const float* __restrict__ Ws, const float* __restrict__ Wi,
    const float* __restrict__ Wr,
    short* __restrict__ Whi, short* __restrict__ Wlo)
{
  int t = blockIdx.x * 256 + threadIdx.x;   // 6144 total
  if (t >= 6144) return;
  int m   = t >> 11;
  int rem = t & 2047;
  int kf  = rem >> 9;
  int kg  = (rem >> 7) & 3;
  int c   = rem & 127;
  const float* W = (m == 0) ? Ws : ((m == 1) ? Wi : Wr);
  short hb[8], lb[8];
#pragma unroll
  for (int j = 0; j < 8; j++) {
    float w = W[(size_t)(kf * 32 + kg * 8 + j) * NFEAT + c];
    unsigned short h = f2bf(w);
    hb[j] = (short)h;
    lb[j] = (short)f2bf(w - bf2f(h));
  }
  int base = ((m * 16 + kf * 4 + kg) << 10) + (c << 3);
  *(short8*)&Whi[base] = *(short8*)hb;
  *(short8*)&Wlo[base] = *(short8*)lb;
}

// ---------------------------------------------------------------------------
// K1 (MFMA, split-bf16): P_w = feature @ W_w + b_w + feature  for w in {s,i,r}
// plus per-column sum/sumsq.  P ≈ Ah·Wh + Al·Wh + Ah·Wl (fp32 accum).
// Grid-stride over 64-row tiles; 512 threads = 8 waves, wave wv owns cols
// [wv*16, wv*16+16) of all 3 matrices.  B frags loaded coalesced from Whi/Wlo.
// ---------------------------------------------------------------------------
__global__ __launch_bounds__(512, 3) void k1_gemm(
    const float* __restrict__ feat,
    const short* __restrict__ Whi, const short* __restrict__ Wlo,
    const float* __restrict__ bs, const float* __restrict__ bi,
    const float* __restrict__ br,
    float* __restrict__ Pout,    // 3 consecutive N x 128 matrices
    float* __restrict__ stats,   // 6*128
    int N, int ntiles)
{
  __shared__ short Ah[64 * LDA];
  __shared__ short Al[64 * LDA];

  const int tid  = threadIdx.x;
  const int lane = tid & 63;
  const int wv   = tid >> 6;
  const int colb = wv * 16 + (lane & 15);
  const int kg   = lane >> 4;         // 0..3
  const int krow = kg * 8;

  const float bias[3] = {bs[colb], bi[colb], br[colb]};
  float ssum[3] = {0.f, 0.f, 0.f}, ssq[3] = {0.f, 0.f, 0.f};
  const size_t nf = (size_t)N * NFEAT;

  for (int tile = blockIdx.x; tile < ntiles; tile += gridDim.x) {
    const int row0 = tile * 64;
    __syncthreads();                  // prior epilogue LDS readers done
    // ---- stage A tile (64 x 128), split hi/lo into LDS
    {
      int r = tid >> 3, o = tid & 7;  // 8 threads/row, 16 f32 each
      int gr = row0 + r; if (gr >= N) gr = N - 1;
      const float4* s4 = (const float4*)(feat + (size_t)gr * NFEAT + o * 16);
      short hbuf[16], lbuf[16];
#pragma unroll
      for (int q = 0; q < 4; q++) {
        float4 f = s4[q];
        float xs[4] = {f.x, f.y, f.z, f.w};
#pragma unroll
        for (int cc = 0; cc < 4; cc++) {
          unsigned short h = f2bf(xs[cc]);
          hbuf[q * 4 + cc] = (short)h;
          lbuf[q * 4 + cc] = (short)f2bf(xs[cc] - bf2f(h));
        }
      }
      short* dh = &Ah[r * LDA + o * 16];
      short* dl = &Al[r * LDA + o * 16];
      *(short8*)(dh)     = *(short8*)(hbuf);
      *(short8*)(dh + 8) = *(short8*)(hbuf + 8);
      *(short8*)(dl)     = *(short8*)(lbuf);
      *(short8*)(dl + 8) = *(short8*)(lbuf + 8);
    }
    __syncthreads();

    // ---- MFMA main loop
    f32x4 acc[3][4];
#pragma unroll
    for (int m = 0; m < 3; m++)
#pragma unroll
      for (int rf = 0; rf < 4; rf++)
        acc[m][rf] = (f32x4){0.f, 0.f, 0.f, 0.f};

#pragma unroll
    for (int kf = 0; kf < 4; kf++) {
      short8 ah[4], al[4];
#pragma unroll
      for (int rf = 0; rf < 4; rf++) {
        int off = (rf * 16 + (lane & 15)) * LDA + kf * 32 + krow;
        ah[rf] = *(const short8*)&Ah[off];
        al[rf] = *(const short8*)&Al[off];
      }
#pragma unroll
      for (int m = 0; m < 3; m++) {
        int fb = ((m * 16 + kf * 4 + kg) << 10) + (colb << 3);
        short8 bh = *(const short8*)&Whi[fb];
        short8 bl = *(const short8*)&Wlo[fb];
#pragma unroll
        for (int rf = 0; rf < 4; rf++) {
          acc[m][rf] = __builtin_amdgcn_mfma_f32_16x16x32_bf16(
              ah[rf], bh, acc[m][rf], 0, 0, 0);
          acc[m][rf] = __builtin_amdgcn_mfma_f32_16x16x32_bf16(
              al[rf], bh, acc[m][rf], 0, 0, 0);
          acc[m][rf] = __builtin_amdgcn_mfma_f32_16x16x32_bf16(
              ah[rf], bl, acc[m][rf], 0, 0, 0);
        }
      }
    }

    // ---- epilogue: + bias + residual(from LDS), store P, accumulate stats
#pragma unroll
    for (int rf = 0; rf < 4; rf++) {
      int lrb = rf * 16 + kg * 4;
#pragma unroll
      for (int g = 0; g < 4; g++) {
        int lr = lrb + g;
        int gr = row0 + lr;
        bool ok = gr < N;
        float res = bf2f((unsigned short)Ah[lr * LDA + colb]) +
                    bf2f((unsigned short)Al[lr * LDA + colb]);
#pragma unroll
        for (int m = 0; m < 3; m++) {
          float v = acc[m][rf][g] + bias[m] + res;
          if (ok) {
            Pout[(size_t)m * nf + (size_t)gr * NFEAT + colb] = v;
            ssum[m] += v;
            ssq[m]  += v * v;
          }
        }
      }
    }
  }

  // ---- one atomic set per block (stats accumulated across tiles)
#pragma unroll
  for (int m = 0; m < 3; m++) {
    float s = ssum[m], q = ssq[m];
    s += __shfl_xor(s, 16); s += __shfl_xor(s, 32);
    q += __shfl_xor(q, 16); q += __shfl_xor(q, 32);
    if (kg == 0) {
      unsafeAtomicAdd(&stats[m * 256 + colb], s);
      unsafeAtomicAdd(&stats[m * 256 + 128 + colb], q);
    }
  }
}

// ---------------------------------------------------------------------------
// K2: grid=7.  Block 0: BN scale/shift (384) + folded bias cb (3).
// Blocks 1..6: MT outputs (1536 total), each a 128-deep dot.
//   logits = S@M1 + I@M3 + R@M4 + NB@M2 + cb
// MT layout: MT[cl*512 + part*128 + k], part: 0=S 1=I 2=R 3=NB
// ---------------------------------------------------------------------------
__global__ void k2_params(
    const float* __restrict__ stats,
    const float* __restrict__ gamma, const float* __restrict__ beta,
    const float* __restrict__ WtoI, const float* __restrict__ btoI,
    const float* __restrict__ WtoR, const float* __restrict__ btoR,
    const float* __restrict__ Wout, const float* __restrict__ bout,
    float* __restrict__ bn,   // 6*128: [w]{a[128], b[128]}
    float* __restrict__ MT,   // 3*512
    float* __restrict__ cb,   // 4
    int N)
{
  const int tid = threadIdx.x;
  const int bid = blockIdx.x;
  const float invN = 1.0f / (float)N;

  if (bid == 0) {
    for (int t = tid; t < 384; t += 256) {
      int w = t >> 7, c = t & 127;
      float sm = stats[w * 256 + c];
      float sq = stats[w * 256 + 128 + c];
      float m = sm * invN;
      float v = sq * invN - m * m;
      float rinv = rsqrtf(v + EPSBN);
      float a = gamma[c] * rinv;
      bn[w * 256 + c] = a;
      bn[w * 256 + 128 + c] = beta[c] - m * a;
    }
    if (tid < 3) {
      float s = bout[tid];
      for (int f = 0; f < 128; f++) {
        s = fmaf(btoI[f], Wout[(128 + f) * 3 + tid] - Wout[f * 3 + tid], s);
        s = fmaf(btoR[f], Wout[(256 + f) * 3 + tid] - Wout[(128 + f) * 3 + tid], s);
      }
      cb[tid] = s;
    }
    return;
  }

  int t = (bid - 1) * 256 + tid;      // 0..1535
  int cl = t / 512;
  int idx = t - cl * 512;
  int part = idx >> 7, k = idx & 127;
  float val;
  if (part == 0) {            // S: Wo1 + WtoI_top @ (Wo2-Wo1)
    float s = Wout[k * 3 + cl];
    for (int f = 0; f < 128; f++)
      s = fmaf(WtoI[k * 128 + f],
               Wout[(128 + f) * 3 + cl] - Wout[f * 3 + cl], s);
    val = s;
  } else if (part == 1) {     // I: Wo2 + WtoR @ (Wo3-Wo2)
    float s = Wout[(128 + k) * 3 + cl];
    for (int f = 0; f < 128; f++)
      s = fmaf(WtoR[k * 128 + f],
               Wout[(256 + f) * 3 + cl] - Wout[(128 + f) * 3 + cl], s);
    val = s;
  } else if (part == 2) {     // R: Wo3
    val = Wout[(256 + k) * 3 + cl];
  } else {                    // NB: WtoI_bot @ (Wo2-Wo1)
    float s = 0.f;
    for (int f = 0; f < 128; f++)
      s = fmaf(WtoI[(128 + k) * 128 + f],
               Wout[(128 + f) * 3 + cl] - Wout[f * 3 + cl], s);
    val = s;
  }
  MT[cl * 512 + idx] = val;
}

// ---------------------------------------------------------------------------
// K3 pipeline: CSR build by dst, then atomic-free gather.
// ---------------------------------------------------------------------------
__global__ __launch_bounds__(256) void k_hist(
    const int* __restrict__ eidx, int* __restrict__ deg, int E)
{
  int e = blockIdx.x * 256 + threadIdx.x;
  if (e < E) atomicAdd(&deg[eidx[E + e]], 1);
}

__global__ __launch_bounds__(256) void k_scan1(
    const int* __restrict__ deg, int* __restrict__ part,
    int* __restrict__ bsum, int N)
{
  __shared__ int sc[256];
  const int tid = threadIdx.x;
  const int base = blockIdx.x * 1024 + tid * 4;
  int v[4];
#pragma unroll
  for (int j = 0; j < 4; j++) {
    int i = base + j;
    v[j] = (i < N) ? deg[i] : 0;
  }
  int tsum = v[0] + v[1] + v[2] + v[3];
  sc[tid] = tsum;
  __syncthreads();
  for (int off = 1; off < 256; off <<= 1) {
    int x = (tid >= off) ? sc[tid - off] : 0;
    __syncthreads();
    sc[tid] += x;
    __syncthreads();
  }
  if (tid == 255) bsum[blockIdx.x] = sc[255];
  int run = sc[tid] - tsum;
#pragma unroll
  for (int j = 0; j < 4; j++) {
    int i = base + j;
    if (i < N) part[i] = run;
    run += v[j];
  }
}

__global__ __launch_bounds__(256) void k_scan2(int* __restrict__ bsum, int nblk)
{
  __shared__ int sc[256];
  const int tid = threadIdx.x;
  int v = (tid < nblk) ? bsum[tid] : 0;
  sc[tid] = v;
  __syncthreads();
  for (int off = 1; off < 256; off <<= 1) {
    int x = (tid >= off) ? sc[tid - off] : 0;
    __syncthreads();
    sc[tid] += x;
    __syncthreads();
  }
  if (tid < nblk) bsum[tid] = sc[tid] - v;
}

__global__ __launch_bounds__(256) void k_scan3(
    const int* __restrict__ part, const int* __restrict__ bsum,
    int* __restrict__ rowstart, int* __restrict__ cursor, int N)
{
  int i = blockIdx.x * 256 + threadIdx.x;
  if (i < N) {
    int v = part[i] + bsum[i >> 10];
    rowstart[i] = v;
    cursor[i] = v;
  }
}

__global__ __launch_bounds__(256) void k_build(
    const int* __restrict__ eidx, const float* __restrict__ ew,
    int* __restrict__ cursor, int* __restrict__ srcb, float* __restrict__ wb,
    int E)
{
  int e = blockIdx.x * 256 + threadIdx.x;
  if (e < E) {
    int dst = eidx[E + e];
    int slot = atomicAdd(&cursor[dst], 1);
    srcb[slot] = eidx[e];
    wb[slot] = ew[e];
  }
}

// gather + logit fold: per dst row, NBrow = sum relu(bn_i(Pi[src]))*w, then
// logit3[r] = NBrow @ M2  (32 lanes/row, shfl reduce).  NB never materialized.
__global__ __launch_bounds__(256) void k_gather(
    const float* __restrict__ Pi,
    const int* __restrict__ rowstart, const int* __restrict__ deg,
    const int* __restrict__ srcb, const float* __restrict__ wb,
    const float* __restrict__ bn, const float* __restrict__ MT,
    float* __restrict__ logit3, int N)
{
  int r = blockIdx.x * 8 + (threadIdx.x >> 5);
  if (r >= N) return;
  const int c = (threadIdx.x & 31) * 4;

  const int rs = rowstart[r];
  const int d  = deg[r];
  float4 a = *(const float4*)&bn[256 + c];        // i-matrix scale
  float4 b = *(const float4*)&bn[256 + 128 + c];  // i-matrix shift
  float4 acc = make_float4(0.f, 0.f, 0.f, 0.f);

  for (int s = 0; s < d; s++) {
    int src = srcb[rs + s];
    float w = wb[rs + s];
    float4 x = *(const float4*)&Pi[(size_t)src * NFEAT + c];
    acc.x += fmaxf(fmaf(a.x, x.x, b.x), 0.f) * w;
    acc.y += fmaxf(fmaf(a.y, x.y, b.y), 0.f) * w;
    acc.z += fmaxf(fmaf(a.z, x.z, b.z), 0.f) * w;
    acc.w += fmaxf(fmaf(a.w, x.w, b.w), 0.f) * w;
  }

  float l[3];
#pragma unroll
  for (int cl = 0; cl < 3; cl++) {
    float4 m = *(const float4*)&MT[cl * 512 + 384 + c];
    l[cl] = acc.x * m.x + acc.y * m.y + acc.z * m.z + acc.w * m.w;
  }
#pragma unroll
  for (int off = 1; off < 32; off <<= 1) {
    l[0] += __shfl_xor(l[0], off);
    l[1] += __shfl_xor(l[1], off);
    l[2] += __shfl_xor(l[2], off);
  }
  if ((threadIdx.x & 31) == 0) {
    float4 o = make_float4(l[0], l[1], l[2], 0.f);
    *(float4*)&logit3[(size_t)r * 4] = o;
  }
}

// ---------------------------------------------------------------------------
// K4: per-row fused BN+ReLU, S/I/R dots with folded MT + neighbor logits,
// softmax.  16 lanes per row; lanes mp<3 handle matrices, one lane adds
// the precomputed logit3.
// ---------------------------------------------------------------------------
__global__ __launch_bounds__(256) void k4_final(
    const float* __restrict__ P,   // 3 consecutive N x 128
    const float* __restrict__ logit3,
    const float* __restrict__ bn,
    const float* __restrict__ MT,
    const float* __restrict__ cb,
    float* __restrict__ out, int N)
{
  __shared__ float MTs[1536];
  __shared__ float bns[768];
  const int tid = threadIdx.x;
  for (int i = tid; i < 1536; i += 256) MTs[i] = MT[i];
  for (int i = tid; i < 768; i += 256) bns[i] = bn[i];
  __syncthreads();

  const int row0 = blockIdx.x * 16 + (tid >> 4);
  const int row  = (row0 < N) ? row0 : (N - 1);
  const int p   = tid & 15;
  const int mp  = p >> 2;       // 0=S 1=I 2=R 3=logit3
  const int seg = p & 3;

  float pa0 = 0.f, pa1 = 0.f, pa2 = 0.f;
  if (mp < 3) {
    const float* xsrc = P + ((size_t)mp * N + row) * NFEAT + seg * 32;
#pragma unroll
    for (int i = 0; i < 8; i++) {
      float4 x = *(const float4*)&xsrc[i * 4];
      int c = seg * 32 + i * 4;
      float4 a = *(float4*)&bns[mp * 256 + c];
      float4 b = *(float4*)&bns[mp * 256 + 128 + c];
      x.x = fmaxf(fmaf(a.x, x.x, b.x), 0.f);
      x.y = fmaxf(fmaf(a.y, x.y, b.y), 0.f);
      x.z = fmaxf(fmaf(a.z, x.z, b.z), 0.f);
      x.w = fmaxf(fmaf(a.w, x.w, b.w), 0.f);
      int mo = mp * 128 + c;
      {
        float4 m = *(float4*)&MTs[0 * 512 + mo];
        pa0 += x.x * m.x + x.y * m.y + x.z * m.z + x.w * m.w;
      }
      {
        float4 m = *(float4*)&MTs[1 * 512 + mo];
        pa1 += x.x * m.x + x.y * m.y + x.z * m.z + x.w * m.w;
      }
      {
        float4 m = *(float4*)&MTs[2 * 512 + mo];
        pa2 += x.x * m.x + x.y * m.y + x.z * m.z + x.w * m.w;
      }
    }
  } else if (seg == 0) {
    float4 L = *(const float4*)&logit3[(size_t)row * 4];
    pa0 = L.x; pa1 = L.y; pa2 = L.z;
  }

#pragma unroll
  for (int off = 1; off < 16; off <<= 1) {
    pa0 += __shfl_xor(pa0, off);
    pa1 += __shfl_xor(pa1, off);
    pa2 += __shfl_xor(pa2, off);
  }
  if (p == 0 && row0 < N) {
    float l0 = pa0 + cb[0], l1 = pa1 + cb[1], l2 = pa2 + cb[2];
    float mx = fmaxf(l0, fmaxf(l1, l2));
    float e0 = expf(l0 - mx), e1 = expf(l1 - mx), e2 = expf(l2 - mx);
    float inv = 1.f / (e0 + e1 + e2);
    out[(size_t)row0 * 3 + 0] = e0 * inv;
    out[(size_t)row0 * 3 + 1] = e1 * inv;
    out[(size_t)row0 * 3 + 2] = e2 * inv;
  }
}

// ---------------------------------------------------------------------------
extern "C" void kernel_launch(void* const* d_in, const int* in_sizes, int n_in,
                              void* d_out, int out_size, void* d_ws, size_t ws_size,
                              hipStream_t stream)
{
  const float* feat  = (const float*)d_in[0];
  const int*   eidx  = (const int*)  d_in[1];
  const float* ew    = (const float*)d_in[2];
  const float* Ws    = (const float*)d_in[3];
  const float* bs    = (const float*)d_in[4];
  const float* Wi    = (const float*)d_in[5];
  const float* bi    = (const float*)d_in[6];
  const float* Wr    = (const float*)d_in[7];
  const float* br    = (const float*)d_in[8];
  const float* gamma = (const float*)d_in[9];
  const float* beta  = (const float*)d_in[10];
  const float* WtoI  = (const float*)d_in[11];
  const float* btoI  = (const float*)d_in[12];
  const float* WtoR  = (const float*)d_in[13];
  const float* btoR  = (const float*)d_in[14];
  const float* Wout  = (const float*)d_in[15];
  const float* bout  = (const float*)d_in[16];

  const int N = in_sizes[0] / NFEAT;
  const int E = in_sizes[2];
  float* out = (float*)d_out;

  const size_t nf = (size_t)N * NFEAT;
  float* P      = (float*)d_ws;         // 3*nf
  float* logit3 = P + 3 * nf;           // 4*N
  float* stats  = logit3 + 4 * (size_t)N; // 768
  float* bn     = stats + 768;          // 768
  float* MT     = bn + 768;             // 1536
  float* cb     = MT + 1536;            // 4
  int*   deg      = (int*)(cb + 4);     // N
  int*   rowstart = deg + N;            // N
  int*   cursor   = rowstart + N;       // N
  int*   part     = cursor + N;         // N
  int*   bsum     = part + N;           // 256
  int*   srcb     = bsum + 256;         // E
  float* wb       = (float*)(srcb + E); // E
  short* Whi      = (short*)(wb + E);   // 49152
  short* Wlo      = Whi + 49152;        // 49152

  hipMemsetAsync(stats, 0, 768 * sizeof(float), stream);
  hipMemsetAsync(deg, 0, (size_t)N * sizeof(int), stream);

  const int nt    = (N + 63) / 64;
  const int g1    = (nt + 2) / 3;               // 3 tiles per block
  const int nscan = (N + 1023) / 1024;
  const int nb256 = (N + 255) / 256;
  const int eb256 = (E + 255) / 256;

  k0_wsplit<<<24, 256, 0, stream>>>(Ws, Wi, Wr, Whi, Wlo);
  k1_gemm<<<g1, 512, 0, stream>>>(feat, Whi, Wlo, bs, bi, br, P, stats, N, nt);
  k2_params<<<7, 256, 0, stream>>>(stats, gamma, beta, WtoI, btoI, WtoR, btoR,
                                   Wout, bout, bn, MT, cb, N);

  // CSR build (independent of k1/k2 results)
  k_hist <<<eb256, 256, 0, stream>>>(eidx, deg, E);
  k_scan1<<<nscan, 256, 0, stream>>>(deg, part, bsum, N);
  k_scan2<<<1, 256, 0, stream>>>(bsum, nscan);
  k_scan3<<<nb256, 256, 0, stream>>>(part, bsum, rowstart, cursor, N);
  k_build<<<eb256, 256, 0, stream>>>(eidx, ew, cursor, srcb, wb, E);

  k_gather<<<(N + 7) / 8, 256, 0, stream>>>(P + nf, rowstart, deg, srcb, wb,
                                            bn, MT, logit3, N);
  k4_final<<<(N + 15) / 16, 256, 0, stream>>>(P, logit3, bn, MT, cb, out, N);
}